// Round 6
// baseline (22.985 us; speedup 1.0000x reference)
//
#include <hip/hip_runtime.h>

namespace {

typedef float v2f  __attribute__((ext_vector_type(2)));
typedef float v4f  __attribute__((ext_vector_type(4)));
typedef float f32x16 __attribute__((ext_vector_type(16)));
typedef short bf16x8 __attribute__((ext_vector_type(8)));
typedef unsigned short ushort;
typedef unsigned short us8 __attribute__((ext_vector_type(8)));
typedef unsigned int v4u __attribute__((ext_vector_type(4)));
typedef __fp16 h2 __attribute__((ext_vector_type(2)));

constexpr int NDIM = 32;
constexpr int HDIM = 64;
constexpr int ODIM = 32;
constexpr float PAIRS = 496.0f;

// float -> bf16 bits, RTNE (bit-twiddle; cold path)
__device__ __forceinline__ ushort f2bf(float f) {
    unsigned int u = __builtin_bit_cast(unsigned int, f);
    u += 0x7fffu + ((u >> 16) & 1u);
    return (ushort)(u >> 16);
}

// hw packed cvt: dst = {bf16(lo), bf16(hi)} — cvt_pk family lo=src0 convention
// verified on HW in round 5 via cvt_pkrtz used in orientation-sensitive code.
__device__ __forceinline__ unsigned cvt_pk_bf16(float lo, float hi) {
    unsigned r;
    asm("v_cvt_pk_bf16_f32 %0, %1, %2" : "=v"(r) : "v"(lo), "v"(hi));
    return r;
}

// packed f16 add with src0-half splat (same op_sel convention as the
// round-2 HW-verified v_pk_fma_f32 splat).
__device__ __forceinline__ h2 padd_splat_lo(h2 a, h2 b) {
    h2 d;
    asm("v_pk_add_f16 %0, %1, %2 op_sel:[0,0] op_sel_hi:[0,1]"
        : "=v"(d) : "v"(a), "v"(b));
    return d;
}
__device__ __forceinline__ h2 padd_splat_hi(h2 a, h2 b) {
    h2 d;
    asm("v_pk_add_f16 %0, %1, %2 op_sel:[1,0] op_sel_hi:[1,1]"
        : "=v"(d) : "v"(a), "v"(b));
    return d;
}

// ---------------------------------------------------------------------------
// Precompute — byte-identical logic to the round-5 verified version.
// ---------------------------------------------------------------------------
__global__ __launch_bounds__(64) void kan_precompute(
    const float* __restrict__ phi_w2, const float* __restrict__ phi_b2,
    const float* __restrict__ psi_w1, const float* __restrict__ psi_b1,
    ushort* __restrict__ Bfrag, float* __restrict__ cconst)
{
    __shared__ float pw2s[32 * 64];
    __shared__ float pw1s[32 * 36];

    const int s = blockIdx.x >> 2, c = blockIdx.x & 3;
    const int lane = threadIdx.x;
    const int hbase = (c & 1) * 32;
    const int off   = (c >> 1) * ODIM;

#pragma unroll
    for (int it = 0; it < 8; ++it) {
        const int idx = it * 256 + lane * 4;
        *(v4f*)&pw2s[idx] = *(const v4f*)(phi_w2 + idx);
    }
#pragma unroll
    for (int it = 0; it < 16; ++it) {
        const int idx = it * 64 + lane;
        const int r = idx >> 5, col = idx & 31;
        pw1s[r * 36 + col] = psi_w1[(hbase + r) * 2 * ODIM + off + col];
    }
    __syncthreads();

    const int row = lane & 31, half = lane >> 5;
    v4f w1r[8];
#pragma unroll
    for (int t = 0; t < 8; ++t) w1r[t] = *(const v4f*)&pw1s[row * 36 + 4 * t];

    us8 out8;
#pragma unroll
    for (int e = 0; e < 8; ++e) {
        const int k = 16 * s + 8 * half + e;
        float m = 0.f;
#pragma unroll
        for (int o = 0; o < 32; ++o)
            m = fmaf(w1r[o >> 2][o & 3], pw2s[o * 64 + k], m);
        out8[e] = f2bf(m);
    }
    *(us8*)(Bfrag + (size_t)(blockIdx.x * 64 + lane) * 8) = out8;

    if (blockIdx.x == 0) {
        float cch = psi_b1[lane];
#pragma unroll
        for (int o = 0; o < ODIM; ++o)
            cch = fmaf(psi_w1[lane * 2 * ODIM + o] + psi_w1[lane * 2 * ODIM + ODIM + o],
                       phi_b2[o], cch);
        cconst[lane] = cch;
    }
}

// ---------------------------------------------------------------------------
// Main: one wave per batch, 4 waves/block. Two-phase MFMA keeps peak VGPR low.
// ---------------------------------------------------------------------------
__global__ __launch_bounds__(256, 4) void kan_main(
    const float* __restrict__ x, const float* __restrict__ phi_w1,
    const float* __restrict__ phi_b1, const float* __restrict__ psi_w2,
    const float* __restrict__ psi_b2, const ushort* __restrict__ Bfrag,
    const float* __restrict__ cconst, float* __restrict__ out)
{
    __shared__ v4u  Blds[1024];       // 16 KB staged B-fragments (linear copy)
    __shared__ float sred[4][HDIM];   // 1 KB

    const int tid  = threadIdx.x;
    const int wave = tid >> 6;
    const int lane = tid & 63;
    const int batch = blockIdx.x * 4 + wave;
    const int row  = lane & 31;
    const int half = lane >> 5;
    const bool hi  = lane >= 32;

    // ---- issue Bfrag global loads early (latency hides under stage 1) --
    const v4u* gB = (const v4u*)Bfrag;
    const v4u t0 = gB[tid];
    const v4u t1 = gB[tid + 256];
    const v4u t2 = gB[tid + 512];
    const v4u t3 = gB[tid + 768];

    const float xn  = x[(size_t)batch * NDIM + row];
    const float cc0 = cconst[row];
    const float cc1 = cconst[32 + row];

    // ---- stage 1: h1 in A-fragment layout (hw packed bf16 cvt) ---------
    bf16x8 afrag[4];
#pragma unroll
    for (int s = 0; s < 4; ++s) {
        const int kb = 16 * s + 8 * half;
        const v4f w1a = *(const v4f*)(phi_w1 + kb);
        const v4f w1b = *(const v4f*)(phi_w1 + kb + 4);
        const v4f b1a = *(const v4f*)(phi_b1 + kb);
        const v4f b1b = *(const v4f*)(phi_b1 + kb + 4);
        float h[8];
#pragma unroll
        for (int e = 0; e < 4; ++e) h[e]     = fmaxf(fmaf(xn, w1a[e], b1a[e]), 0.f);
#pragma unroll
        for (int e = 0; e < 4; ++e) h[4 + e] = fmaxf(fmaf(xn, w1b[e], b1b[e]), 0.f);
        v4u u;
#pragma unroll
        for (int w = 0; w < 4; ++w) u[w] = cvt_pk_bf16(h[2 * w], h[2 * w + 1]);
        afrag[s] = __builtin_bit_cast(bf16x8, u);
    }

    // ---- commit staged B to LDS ----------------------------------------
    Blds[tid]       = t0;
    Blds[tid + 256] = t1;
    Blds[tid + 512] = t2;
    Blds[tid + 768] = t3;
    __syncthreads();

    const bf16x8* Bf = (const bf16x8*)Blds;

    // exchange: two C-tiles (cols h0-31 / h32-63) -> per-lane packed pairs
    // for h = lane. Same verified round-3/5 shfl logic, on h2 payloads.
    // q -> n0 = ((2q)&3) + 8*((2q)>>2); out[n0/2] = {v[n0],v[n0+1]},
    // out[n0/2+2] = {v[n0+4],v[n0+5]}.
    auto exchange = [&](const f32x16& lo32, const f32x16& hi32, h2* outp) {
#pragma unroll
        for (int q = 0; q < 8; ++q) {
            const h2 cl = __builtin_amdgcn_cvt_pkrtz(lo32[2 * q], lo32[2 * q + 1]);
            const h2 ch = __builtin_amdgcn_cvt_pkrtz(hi32[2 * q], hi32[2 * q + 1]);
            const h2 own = hi ? ch : cl;
            const h2 snd = hi ? cl : ch;
            const unsigned su = __builtin_bit_cast(unsigned, snd);
            const unsigned ou = (unsigned)__shfl_xor((int)su, 32);
            const h2 oth = __builtin_bit_cast(h2, ou);
            const int n0 = ((2 * q) & 3) + 8 * ((2 * q) >> 2);
            outp[(n0 >> 1)]     = hi ? oth : own;
            outp[(n0 >> 1) + 2] = hi ? own : oth;
        }
    };

    // ---- phase A: A-side MFMAs (cols 0..63), cconst folded in ----------
    h2 Ah[16], Bh[16];
    {
        f32x16 a0, a1;
#pragma unroll
        for (int r = 0; r < 16; ++r) { a0[r] = cc0; a1[r] = cc1; }
#pragma unroll
        for (int s = 0; s < 4; ++s) {
            const bf16x8 b0 = Bf[(s * 4 + 0) * 64 + lane];
            const bf16x8 b1 = Bf[(s * 4 + 1) * 64 + lane];
            a0 = __builtin_amdgcn_mfma_f32_32x32x16_bf16(afrag[s], b0, a0, 0, 0, 0);
            a1 = __builtin_amdgcn_mfma_f32_32x32x16_bf16(afrag[s], b1, a1, 0, 0, 0);
        }
        exchange(a0, a1, Ah);
    }
    // ---- phase B: B-side MFMAs (cols 64..127) --------------------------
    {
        f32x16 a2, a3;
#pragma unroll
        for (int r = 0; r < 16; ++r) { a2[r] = 0.f; a3[r] = 0.f; }
#pragma unroll
        for (int s = 0; s < 4; ++s) {
            const bf16x8 b2 = Bf[(s * 4 + 2) * 64 + lane];
            const bf16x8 b3 = Bf[(s * 4 + 3) * 64 + lane];
            a2 = __builtin_amdgcn_mfma_f32_32x32x16_bf16(afrag[s], b2, a2, 0, 0, 0);
            a3 = __builtin_amdgcn_mfma_f32_32x32x16_bf16(afrag[s], b3, a3, 0, 0, 0);
        }
        exchange(a2, a3, Bh);
    }

    // ---- stage 3: S = sum_{i<j} relu(A[i]+B[j]), packed f16 ------------
    // groups: i vs Bh[p]={B[2p],B[2p+1]}; even i=2m starts at p=m with
    // fdot2 mask {0,1} (j=2m invalid); odd i=2m+1 starts at p=m+1.
    // pairs = 256*2 - 16 = 496. ✓
    const h2 zero2 = {(__fp16)0.f, (__fp16)0.f};
    const h2 one2  = {(__fp16)1.f, (__fp16)1.f};
    const h2 m01   = {(__fp16)0.f, (__fp16)1.f};
    float acc[8] = {0.f, 0.f, 0.f, 0.f, 0.f, 0.f, 0.f, 0.f};

#pragma unroll
    for (int i = 0; i < 31; ++i) {
        const int m = i >> 1;
        const h2 ai = Ah[m];
        if ((i & 1) == 0) {
            const h2 t = padd_splat_lo(ai, Bh[m]);
            const h2 r = __builtin_elementwise_max(t, zero2);
            acc[m & 7] = __builtin_amdgcn_fdot2(r, m01, acc[m & 7], false);
#pragma unroll
            for (int p = m + 1; p < 16; ++p) {
                const h2 tt = padd_splat_lo(ai, Bh[p]);
                const h2 rr = __builtin_elementwise_max(tt, zero2);
                acc[p & 7] = __builtin_amdgcn_fdot2(rr, one2, acc[p & 7], false);
            }
        } else {
#pragma unroll
            for (int p = m + 1; p < 16; ++p) {
                const h2 tt = padd_splat_hi(ai, Bh[p]);
                const h2 rr = __builtin_elementwise_max(tt, zero2);
                acc[p & 7] = __builtin_amdgcn_fdot2(rr, one2, acc[p & 7], false);
            }
        }
    }
    const float S = ((acc[0] + acc[1]) + (acc[2] + acc[3])) +
                    ((acc[4] + acc[5]) + (acc[6] + acc[7]));

    sred[wave][lane] = S;   // same-wave producer/consumer

    // ---- epilogue: out[o] = psi_w2[o,:] . S + PAIRS * psi_b2[o] --------
    const int oo = row;
    const float* w2r = psi_w2 + (size_t)oo * HDIM + half * 32;
    float part = 0.f;
#pragma unroll
    for (int r = 0; r < 8; ++r) {
        const v4f w  = *(const v4f*)(w2r + 4 * r);
        const v4f sv = *(const v4f*)&sred[wave][half * 32 + 4 * r];
        part = fmaf(w[0], sv[0], part);
        part = fmaf(w[1], sv[1], part);
        part = fmaf(w[2], sv[2], part);
        part = fmaf(w[3], sv[3], part);
    }
    part += __shfl_down(part, 32);
    if (half == 0)
        out[(size_t)batch * ODIM + oo] = part + PAIRS * psi_b2[oo];
}

} // namespace

extern "C" void kernel_launch(void* const* d_in, const int* in_sizes, int n_in,
                              void* d_out, int out_size, void* d_ws, size_t ws_size,
                              hipStream_t stream)
{
    const float* x      = (const float*)d_in[0];
    const float* phi_w1 = (const float*)d_in[1];
    const float* phi_b1 = (const float*)d_in[2];
    const float* phi_w2 = (const float*)d_in[3];
    const float* phi_b2 = (const float*)d_in[4];
    const float* psi_w1 = (const float*)d_in[5];
    const float* psi_b1 = (const float*)d_in[6];
    const float* psi_w2 = (const float*)d_in[7];
    const float* psi_b2 = (const float*)d_in[8];

    ushort* Bfrag = (ushort*)d_ws;                        // 16 KB
    float* cconst = (float*)((char*)d_ws + 16 * 64 * 8 * sizeof(ushort));
    float* out    = (float*)d_out;

    kan_precompute<<<16, 64, 0, stream>>>(phi_w2, phi_b2, psi_w1, psi_b1, Bfrag, cconst);
    kan_main<<<4096 / 4, 256, 0, stream>>>(x, phi_w1, phi_b1, psi_w2, psi_b2,
                                           Bfrag, cconst, out);
}